// Round 9
// baseline (556.855 us; speedup 1.0000x reference)
//
#include <hip/hip_runtime.h>
#include <cstdint>
#include <cstddef>

// VAE forward, fused bf16-MFMA pipeline.
// Sizes fixed: B=32768, INPUT=1024, HIDDEN=1024, LATENT=128.
//
// R13: amortize + reveal. (a) G4 split into 2 half-M dispatches (2x256
//     blocks, ~51 us each) -> drops below G1 in rocprof top-5 so G1's
//     true duration becomes visible next round; 256 blocks = 1 clean
//     CU-wave each. (b) G1: 256 blocks x 2 n-tiles per block -- xs panel
//     loaded once, prologue ramp halved, B panels L2-warm for tile 2.
//     (c) latent part-2: 64-row quarter-tile dbuf staging with raw
//     s_barrier + counted vmcnt (16 hd-stores/thread are newer than the
//     4 stage loads -> vmcnt(16) retires exactly the loads; kills the
//     implicit full drain of __syncthreads).
// R12 (kept): latent 64-row blocks, 2 blocks/CU, part-1 BK=32 dbuf.
// R11 (kept): G1 ABIT path (A synthesized from xbit in LDS).
// R10 (kept): merged prep (transposes + bitpack).
// R8 (kept): latent fusion (z in LDS), xbit bitmask epilogue for G4.
// R5 (kept): 256x256, 512 thr/8 waves, BK=64, 8-phase counted-vmcnt.
// R3 (kept): XCD-pinned decode. R2 (kept): XOR-swizzled staging.

typedef __bf16 bf16x8 __attribute__((ext_vector_type(8)));
typedef float f32x4 __attribute__((ext_vector_type(4)));

__device__ __forceinline__ unsigned short f32_to_bf16(float f) {
  unsigned int u = __float_as_uint(f);
  u += 0x7fffu + ((u >> 16) & 1u);   // round-to-nearest-even (finite values)
  return (unsigned short)(u >> 16);
}

// ------------- merged prep: 5 transpose-convert jobs + x bitpack -------------
struct TransJob { const float* in; unsigned short* out; int K, N, blkEnd; };

__global__ void prep_k(TransJob j0, TransJob j1, TransJob j2,
                       TransJob j3, TransJob j4,
                       const float* __restrict__ x,
                       unsigned short* __restrict__ xbit,
                       int n4, int castBlocks) {
  __shared__ float tile[32][33];
  int bid = blockIdx.x;
  int tx = threadIdx.x, ty = threadIdx.y;  // block is 32x8
  if (bid >= j4.blkEnd) {
    // ---- bitpack part: x (exactly {0,1}) -> bitmask ----
    int tid = ty * 32 + tx;
    int stride = castBlocks * 256;
    for (int i = (bid - j4.blkEnd) * 256 + tid; i < n4; i += stride) {
      float4 v = reinterpret_cast<const float4*>(x)[i];
      unsigned int nib = (v.x != 0.f ? 1u : 0u) | (v.y != 0.f ? 2u : 0u) |
                         (v.z != 0.f ? 4u : 0u) | (v.w != 0.f ? 8u : 0u);
      unsigned int n1 = __shfl_down(nib, 1, 64);
      unsigned int n2 = __shfl_down(nib, 2, 64);
      unsigned int n3 = __shfl_down(nib, 3, 64);
      if ((tid & 3) == 0)
        xbit[i >> 2] = (unsigned short)(nib | (n1 << 4) | (n2 << 8) | (n3 << 12));
    }
    return;
  }
  // ---- transpose part: fp32 [K][N] -> bf16 [N][K] ----
  TransJob j; int base;
  if (bid < j0.blkEnd)      { j = j0; base = 0; }
  else if (bid < j1.blkEnd) { j = j1; base = j0.blkEnd; }
  else if (bid < j2.blkEnd) { j = j2; base = j1.blkEnd; }
  else if (bid < j3.blkEnd) { j = j3; base = j2.blkEnd; }
  else                      { j = j4; base = j3.blkEnd; }
  int local = bid - base;
  int gxN = j.N >> 5;
  int n0 = (local % gxN) * 32, k0 = (local / gxN) * 32;
#pragma unroll
  for (int r = 0; r < 32; r += 8)
    tile[ty + r][tx] = j.in[(size_t)(k0 + ty + r) * j.N + n0 + tx];
  __syncthreads();
#pragma unroll
  for (int r = 0; r < 32; r += 8)
    j.out[(size_t)(n0 + ty + r) * j.K + k0 + tx] = f32_to_bf16(tile[tx][ty + r]);
}

// async global->LDS, 16B per lane; LDS dest must be contiguous in lane order
__device__ __forceinline__ void gl_lds16(const unsigned short* g, unsigned short* l) {
  __builtin_amdgcn_global_load_lds(
      (__attribute__((address_space(1))) void*)g,
      (__attribute__((address_space(3))) void*)l, 16, 0, 0);
}

// ---------------- GEMM: C = A[M][K] @ BT[N][K]^T + bias ----------------
// 256x256 tile, 512 threads, 8 waves (2Mx4N), BK=64, 8-phase counted-vmcnt
// pipeline. ABIT=1 (G1): A synthesized from xbit in LDS; 256 blocks, each
// computes 2 n-tiles (xs panel reused). ABIT=0 (G4): 256 blocks, 1 tile,
// rows [mBase, mBase+16384). EPI 0: relu->bf16. EPI 2: bernoulli LL
// rowsum via xbit + atomicAdd.
template <int EPI, int TAG, int ABIT>
__global__ __launch_bounds__(512, 2) void gemm256(
    const unsigned short* __restrict__ A, const unsigned short* __restrict__ BT,
    int mBase, int N, int K,
    const float* __restrict__ bias0,
    unsigned short* __restrict__ outb, float* __restrict__ outf,
    const unsigned short* __restrict__ xbit) {
  // 128 KB, carved per variant:
  //  ABIT=0: buf b: A = smem+b*32768, B = smem+b*32768+16384
  //  ABIT=1: As = smem (single), Bs[b] = smem+16384+b*16384, xs = smem+49152
  __shared__ __align__(16) unsigned short smem[65536];

  const int tid = threadIdx.x;
  const int lane = tid & 63;
  const int wave = tid >> 6;
  const int wr = wave >> 2;          // 0..1 (M)
  const int wc = wave & 3;           // 0..3 (N)
  const int lm = lane & 15, lq = lane >> 4;
  const int sw = lm & 7;

  const int bid = blockIdx.x;
  const int xcd = bid & 7;
  const int t8 = bid >> 3;
  int m0, n0base;
  if (ABIT) { m0 = (xcd + 8 * (t8 >> 1)) * 256; n0base = (t8 & 1) * 512; }
  else      { m0 = mBase + (xcd + 8 * (t8 >> 2)) * 256; n0base = (t8 & 3) * 256; }
  const int NT = K >> 6;

  unsigned short* const smemp = smem;
  auto Abuf = [&](int b) -> unsigned short* {
    return ABIT ? smemp : smemp + b * 32768;
  };
  auto Bbuf = [&](int b) -> unsigned short* {
    return ABIT ? smemp + 16384 + b * 16384 : smemp + b * 32768 + 16384;
  };

  // Half-stage regions (16 KB each = 2 chunks/thread):
  //  A1: rows {0-63,128-191}   A2: rows {64-127,192-255}
  //  B1: rows {0-31,64-95,128-159,192-223}   B2: B1+32
  const unsigned short* gpA[2];
  const unsigned short* gpB0[2];   // n0-independent B base
  int loA[2], loB[2], xaddr[2];
#pragma unroll
  for (int r = 0; r < 2; ++r) {
    int c = tid + 512 * r, rl = c >> 3, q8 = c & 7;
    int rowA = (rl & 63) + ((rl >> 6) << 7);   // A1 row
    int rowB = (rl & 31) + ((rl >> 5) << 6);   // B1 row
    int qgA = q8 ^ (rowA & 7);
    gpA[r] = A + (size_t)(m0 + rowA) * K + qgA * 8;
    gpB0[r] = BT + (size_t)rowB * K + (q8 ^ (rowB & 7)) * 8;
    loA[r] = rowA * 64 + q8 * 8;
    loB[r] = rowB * 64 + q8 * 8;
    xaddr[r] = rowA * 128 + qgA;               // xs byte addr (tile 0)
  }

  // bits -> bf16 expansion of A for K-tile t (ABIT only).
  auto expandA = [&](int t) {
    const unsigned char* xsb = reinterpret_cast<const unsigned char*>(smemp + 49152);
    unsigned short* As = smemp;
#pragma unroll
    for (int r = 0; r < 2; ++r) {
#pragma unroll
      for (int h = 0; h < 2; ++h) {   // h=0: A1 row; h=1: A2 = +64 rows
        unsigned int b = xsb[xaddr[r] + h * 8192 + 8 * t];
        unsigned int o0 = ((b & 1u)        ? 0x3F80u : 0u) | ((b & 2u)   ? 0x3F800000u : 0u);
        unsigned int o1 = (((b >> 2) & 1u) ? 0x3F80u : 0u) | ((b & 8u)   ? 0x3F800000u : 0u);
        unsigned int o2 = (((b >> 4) & 1u) ? 0x3F80u : 0u) | ((b & 32u)  ? 0x3F800000u : 0u);
        unsigned int o3 = (((b >> 6) & 1u) ? 0x3F80u : 0u) | ((b & 128u) ? 0x3F800000u : 0u);
        *reinterpret_cast<uint4*>(As + loA[r] + h * 4096) = make_uint4(o0, o1, o2, o3);
      }
    }
  };

  const int aRow = (wr * 128 + lm) * 64;
  const int bRow = (wc * 64 + lm) * 64;
  const int c0 = ((0 | lq) ^ sw) * 8;
  const int c1 = ((4 | lq) ^ sw) * 8;

  const int NTL = ABIT ? 2 : 1;
  for (int ntl = 0; ntl < NTL; ++ntl) {
    const int n0 = n0base + ntl * 256;
    const unsigned short* gB[2];
#pragma unroll
    for (int r = 0; r < 2; ++r) gB[r] = gpB0[r] + (size_t)n0 * K;

    auto stage = [&](int kind, int buf, int kt) {
#pragma unroll
      for (int r = 0; r < 2; ++r) {
        if (kind == 0)      { if (!ABIT) gl_lds16(gpA[r] + kt * 64,          Abuf(buf) + loA[r]); }
        else if (kind == 3) { if (!ABIT) gl_lds16(gpA[r] + 64 * K + kt * 64, Abuf(buf) + loA[r] + 4096); }
        else if (kind == 1) gl_lds16(gB[r] + kt * 64,          Bbuf(buf) + loB[r]);
        else                gl_lds16(gB[r] + 32 * K + kt * 64, Bbuf(buf) + loB[r] + 2048);
      }
    };

    // ---- prologue ----
    if (ABIT) {
      if (ntl == 0) {
        const unsigned short* xp = xbit + (size_t)m0 * 64;   // 32 KB panel
        unsigned short* xs = smemp + 49152;
#pragma unroll
        for (int i = 0; i < 4; ++i)
          gl_lds16(xp + (tid + 512 * i) * 8, xs + (tid + 512 * i) * 8);
      }
      stage(1, 0, 0); stage(2, 0, 0);          // B(t0)
      stage(1, 1, 1); stage(2, 1, 1);          // B(t1)
      if (ntl == 0) { asm volatile("s_waitcnt vmcnt(8)" ::: "memory"); }  // xs landed
      expandA(0);
      // tile-2: vmcnt counts leftover epilogue stores too -> conservative
      asm volatile("s_waitcnt vmcnt(4) lgkmcnt(0)" ::: "memory");
      __builtin_amdgcn_s_barrier();
    } else {
      stage(0, 0, 0); stage(1, 0, 0); stage(2, 0, 0); stage(3, 0, 0);
      stage(0, 1, 1); stage(1, 1, 1); stage(2, 1, 1);
      asm volatile("s_waitcnt vmcnt(6)" ::: "memory");
      __builtin_amdgcn_s_barrier();
    }

    f32x4 acc[8][4] = {};

    for (int t = 0; t < NT; ++t) {
      const int b = t & 1;
      const unsigned short* Ab = Abuf(b);
      const unsigned short* Bb = Bbuf(b);
      bf16x8 af[4][2], bf1[2][2], bf2[2][2];

      // ---- P1: af-low + bf1 reads; stage A2(t+1) [non-ABIT] ----
#pragma unroll
      for (int i = 0; i < 4; ++i) {
        af[i][0] = *reinterpret_cast<const bf16x8*>(Ab + aRow + i * 1024 + c0);
        af[i][1] = *reinterpret_cast<const bf16x8*>(Ab + aRow + i * 1024 + c1);
      }
#pragma unroll
      for (int j = 0; j < 2; ++j) {
        bf1[j][0] = *reinterpret_cast<const bf16x8*>(Bb + bRow + j * 1024 + c0);
        bf1[j][1] = *reinterpret_cast<const bf16x8*>(Bb + bRow + j * 1024 + c1);
      }
      if (!ABIT && t + 1 < NT) stage(3, (t + 1) & 1, t + 1);
      __builtin_amdgcn_s_barrier();
      asm volatile("s_waitcnt lgkmcnt(0)" ::: "memory");
      __builtin_amdgcn_sched_barrier(0);
      __builtin_amdgcn_s_setprio(1);
#pragma unroll
      for (int s = 0; s < 2; ++s)
#pragma unroll
        for (int i = 0; i < 4; ++i)
#pragma unroll
          for (int j = 0; j < 2; ++j)
            acc[i][j] = __builtin_amdgcn_mfma_f32_16x16x32_bf16(af[i][s], bf1[j][s], acc[i][j], 0, 0, 0);
      __builtin_amdgcn_s_setprio(0);
      __builtin_amdgcn_s_barrier();

      // ---- P2: bf2 reads; stage B1(t+2) [ABIT] / A1(t+2) [non-ABIT] ----
#pragma unroll
      for (int j = 0; j < 2; ++j) {
        bf2[j][0] = *reinterpret_cast<const bf16x8*>(Bb + bRow + (j + 2) * 1024 + c0);
        bf2[j][1] = *reinterpret_cast<const bf16x8*>(Bb + bRow + (j + 2) * 1024 + c1);
      }
      if (t + 2 < NT) stage(ABIT ? 1 : 0, b, t + 2);
      __builtin_amdgcn_s_barrier();
      asm volatile("s_waitcnt lgkmcnt(0)" ::: "memory");
      __builtin_amdgcn_sched_barrier(0);
      __builtin_amdgcn_s_setprio(1);
#pragma unroll
      for (int s = 0; s < 2; ++s)
#pragma unroll
        for (int i = 0; i < 4; ++i)
#pragma unroll
          for (int j = 0; j < 2; ++j)
            acc[i][j + 2] = __builtin_amdgcn_mfma_f32_16x16x32_bf16(af[i][s], bf2[j][s], acc[i][j + 2], 0, 0, 0);
      __builtin_amdgcn_s_setprio(0);
      __builtin_amdgcn_s_barrier();

      // ---- P3: af-high reads; stage B2(t+2) [ABIT] / B1(t+2) [non-ABIT] ----
#pragma unroll
      for (int i = 0; i < 4; ++i) {
        af[i][0] = *reinterpret_cast<const bf16x8*>(Ab + aRow + (64 + i * 16) * 64 + c0);
        af[i][1] = *reinterpret_cast<const bf16x8*>(Ab + aRow + (64 + i * 16) * 64 + c1);
      }
      if (t + 2 < NT) stage(ABIT ? 2 : 1, b, t + 2);
      __builtin_amdgcn_s_barrier();
      asm volatile("s_waitcnt lgkmcnt(0)" ::: "memory");
      __builtin_amdgcn_sched_barrier(0);
      __builtin_amdgcn_s_setprio(1);
#pragma unroll
      for (int s = 0; s < 2; ++s)
#pragma unroll
        for (int i = 0; i < 4; ++i)
#pragma unroll
          for (int j = 0; j < 2; ++j)
            acc[i + 4][j] = __builtin_amdgcn_mfma_f32_16x16x32_bf16(af[i][s], bf1[j][s], acc[i + 4][j], 0, 0, 0);
      __builtin_amdgcn_s_setprio(0);
      __builtin_amdgcn_s_barrier();

      // ---- P4: expand A(t+1) [ABIT] / stage B2(t+2) [non-ABIT]; MFMA C4 ----
      if (ABIT) { if (t + 1 < NT) expandA(t + 1); }
      else      { if (t + 2 < NT) stage(2, b, t + 2); }
      __builtin_amdgcn_s_barrier();
      __builtin_amdgcn_s_setprio(1);
#pragma unroll
      for (int s = 0; s < 2; ++s)
#pragma unroll
        for (int i = 0; i < 4; ++i)
#pragma unroll
          for (int j = 0; j < 2; ++j)
            acc[i + 4][j + 2] = __builtin_amdgcn_mfma_f32_16x16x32_bf16(af[i][s], bf2[j][s], acc[i + 4][j + 2], 0, 0, 0);
      __builtin_amdgcn_s_setprio(0);
      if (ABIT) {
        if (t + 2 < NT) { asm volatile("s_waitcnt vmcnt(4) lgkmcnt(0)" ::: "memory"); }
        else            { asm volatile("s_waitcnt vmcnt(0) lgkmcnt(0)" ::: "memory"); }
      } else {
        if (t + 2 < NT)      { asm volatile("s_waitcnt vmcnt(6)" ::: "memory"); }
        else if (t + 1 < NT) { asm volatile("s_waitcnt vmcnt(0)" ::: "memory"); }
      }
      __builtin_amdgcn_s_barrier();
    }

    if (EPI == 0) {
#pragma unroll
      for (int i = 0; i < 8; ++i)
#pragma unroll
        for (int j = 0; j < 4; ++j) {
          int col = n0 + wc * 64 + j * 16 + lm;
          float bias = bias0[col];
#pragma unroll
          for (int r = 0; r < 4; ++r) {
            int row = m0 + wr * 128 + i * 16 + lq * 4 + r;
            float v = acc[i][j][r] + bias;
            outb[(size_t)row * N + col] = f32_to_bf16(fmaxf(v, 0.f));
          }
        }
    } else {
      const int wpr = N >> 4;   // bitmask words per row
#pragma unroll
      for (int i = 0; i < 8; ++i) {
        float rs[4] = {0.f, 0.f, 0.f, 0.f};
#pragma unroll
        for (int j = 0; j < 4; ++j) {
          int col = n0 + wc * 64 + j * 16 + lm;
          float bias = bias0[col];
          int w16 = (col >> 4);
#pragma unroll
          for (int r = 0; r < 4; ++r) {
            int row = m0 + wr * 128 + i * 16 + lq * 4 + r;
            float l = acc[i][j][r] + bias;
            unsigned short mask = xbit[(size_t)row * wpr + w16];  // broadcast
            float tt = ((mask >> lm) & 1) ? -l : l;
            float sp = fmaxf(tt, 0.f) + __logf(1.f + __expf(-fabsf(tt)));
            rs[r] -= sp;
          }
        }
#pragma unroll
        for (int off = 1; off < 16; off <<= 1)
#pragma unroll
          for (int r = 0; r < 4; ++r) rs[r] += __shfl_xor(rs[r], off, 64);
        if (lm == 0) {
#pragma unroll
          for (int r = 0; r < 4; ++r)
            atomicAdd(&outf[m0 + wr * 128 + i * 16 + lq * 4 + r], rs[r]);
        }
      }
    }
  }
}

// -------- latent_fused: S2 = h @ w2t^T (N=256) -> z/kl -> hd = relu(z@Wd1+bd1) --------
// One block per 64 batch rows (grid 512), 256 thr / 4 waves, 2 blocks/CU.
// Part 1 BK=32 dbuf (R12). Part 2 (R13): 64-row quarter-tiles of wd1t,
// double-buffered, raw s_barrier + counted vmcnt.
__global__ __launch_bounds__(256, 2) void latent_fused(
    const unsigned short* A,                  // h [B][1024] (also hd output)
    const unsigned short* __restrict__ BT,    // w2t [256][1024]
    const unsigned short* __restrict__ WD1,   // wd1t [1024][128]
    const float* __restrict__ bmu, const float* __restrict__ bls,
    const float* __restrict__ bd1,
    const float* __restrict__ eps,            // [B][128]
    unsigned short* hd,                       // [B][1024] (= h buffer)
    float* __restrict__ out) {
  __shared__ __align__(16) unsigned short smem[28672];   // 56 KB
  unsigned short* As0 = smem;              // [64*32]   0..2047
  unsigned short* As1 = smem + 2048;       // [64*32]   2048..4095
  unsigned short* Bs0 = smem + 4096;       // [256*32]  4096..12287
  unsigned short* Bs1 = smem + 12288;      // [256*32]  12288..20479
  unsigned short* zs  = smem + 20480;      // [64*128]  20480..28671
  unsigned short* Bq0 = smem;              // [64*128] part 2 q-buf 0 (overlays)
  unsigned short* Bq1 = smem + 8192;       // [64*128] part 2 q-buf 1

  const int K = 1024;
  const int tid = threadIdx.x;
  const int lane = tid & 63;
  const int wave = tid >> 6;
  const int m0 = blockIdx.x * 64;
  const int lm = lane & 15, lq = lane >> 4;
  const int sw2 = (lm >> 1) & 3;           // BK=32 read swizzle (R7 pattern)

  // ---- part 1 staging: A 256 chunks (1/thread), B 1024 chunks (4/thread)
  const unsigned short* agp;
  const unsigned short* bgp[4];
  {
    int row = tid >> 2, q = tid & 3;
    agp = A + (size_t)(m0 + row) * K + (q ^ ((row >> 1) & 3)) * 8;
  }
#pragma unroll
  for (int r = 0; r < 4; ++r) {
    int c = tid + 256 * r;
    int row = c >> 2, q = c & 3;
    bgp[r] = BT + (size_t)row * K + (q ^ ((row >> 1) & 3)) * 8;
  }

  auto stage1 = [&](int buf, int kt) {
    gl_lds16(agp + kt, (buf ? As1 : As0) + tid * 8);
    unsigned short* Bd = buf ? Bs1 : Bs0;
#pragma unroll
    for (int r = 0; r < 4; ++r) gl_lds16(bgp[r] + kt, Bd + (tid + 256 * r) * 8);
  };

  f32x4 acc[16] = {};

  stage1(0, 0);
  __syncthreads();

  const int aOff = (wave * 16 + lm) * 32 + (lq ^ sw2) * 8;
  for (int t = 0; t < 32; ++t) {
    const int cur = t & 1;
    if (t + 1 < 32) stage1(cur ^ 1, (t + 1) * 32);   // full-tile window
    const unsigned short* Ab = cur ? As1 : As0;
    const unsigned short* Bb = cur ? Bs1 : Bs0;
    bf16x8 af = *reinterpret_cast<const bf16x8*>(Ab + aOff);
#pragma unroll
    for (int j = 0; j < 16; ++j) {
      bf16x8 b = *reinterpret_cast<const bf16x8*>(Bb + (j * 16 + lm) * 32 + (lq ^ sw2) * 8);
      acc[j] = __builtin_amdgcn_mfma_f32_16x16x32_bf16(af, b, acc[j], 0, 0, 0);
    }
    __syncthreads();   // implicit vmcnt(0): stage had a full tile to land
  }

  // part 2 staging: wd1t quarter [64 rows][128 k] -> Bq; 1024 chunks ->
  // 4/thread; slot s of row r holds global chunk s ^ (r&7).
  auto stage2 = [&](int q, int buf) {
    unsigned short* D = buf ? Bq1 : Bq0;
#pragma unroll
    for (int ri = 0; ri < 4; ++ri) {
      int c = tid + 256 * ri;
      int row = c >> 4, slot = c & 15;
      int gc = slot ^ (row & 7);
      gl_lds16(WD1 + (size_t)(q * 64 + row) * 128 + gc * 8, D + c * 8);
    }
  };
  stage2(0, 0);   // overlays dead part-1 As bufs; overlaps z/kl epilogue

  // ---- part 1 epilogue: z -> zs (swizzled), kl -> out ----
  {
    float kl[4] = {0.f, 0.f, 0.f, 0.f};
#pragma unroll
    for (int j = 0; j < 8; ++j) {
      int dim = j * 16 + lm;
      float bm = bmu[dim], bl = bls[dim];
#pragma unroll
      for (int r = 0; r < 4; ++r) {
        int rowl = wave * 16 + lq * 4 + r;                  // local row
        float mu = acc[j][r] + bm;
        float ls = acc[j + 8][r] + bl;
        float e = eps[(size_t)(m0 + rowl) * 128 + dim];
        float zv = fmaf(__expf(ls), e, mu);
        int chunk = (dim >> 3);
        int slot = chunk ^ (rowl & 7);
        zs[rowl * 128 + slot * 8 + (lm & 7)] = f32_to_bf16(zv);
        kl[r] += 0.5f * (__expf(2.f * ls) + mu * mu - 2.f * ls - 1.f);
      }
    }
#pragma unroll
    for (int off = 1; off < 16; off <<= 1)
#pragma unroll
      for (int r = 0; r < 4; ++r) kl[r] += __shfl_xor(kl[r], off, 64);
    if (lm == 0) {
#pragma unroll
      for (int r = 0; r < 4; ++r)
        out[m0 + wave * 16 + lq * 4 + r] = -kl[r];
    }
  }

  // ---- part 2: hd = relu(z @ wd1t^T + bd1), 16 quarter-tiles of 64 cols,
  //      double-buffered; vmcnt(16): the 16 hd-stores/thread issued after
  //      the current quarter's 4 stage loads keep the wait counted ----
  for (int q = 0; q < 16; ++q) {
    if (q == 0) { asm volatile("s_waitcnt vmcnt(0) lgkmcnt(0)" ::: "memory"); }
    else        { asm volatile("s_waitcnt vmcnt(16)" ::: "memory"); }
    __builtin_amdgcn_s_barrier();
    if (q + 1 < 16) stage2(q + 1, (q + 1) & 1);
    const unsigned short* Bq = (q & 1) ? Bq1 : Bq0;
    f32x4 acc2[4] = {};
#pragma unroll
    for (int ks = 0; ks < 4; ++ks) {
      const int cks = (ks * 4 + lq) ^ (lm & 7);
      bf16x8 a0 = *reinterpret_cast<const bf16x8*>(zs + (wave * 16 + lm) * 128 + cks * 8);
#pragma unroll
      for (int j = 0; j < 4; ++j) {
        bf16x8 b = *reinterpret_cast<const bf16x8*>(Bq + (j * 16 + lm) * 128 + cks * 8);
        acc2[j] = __builtin_amdgcn_mfma_f32_16x16x32_bf16(a0, b, acc2[j], 0, 0, 0);
      }
    }
#pragma unroll
    for (int j = 0; j < 4; ++j) {
      int col = q * 64 + j * 16 + lm;
      float bias = bd1[col];
#pragma unroll
      for (int r = 0; r < 4; ++r) {
        int row = m0 + wave * 16 + lq * 4 + r;
        float v = acc2[j][r] + bias;
        hd[(size_t)row * 1024 + col] = f32_to_bf16(fmaxf(v, 0.f));
      }
    }
  }
}

extern "C" void kernel_launch(void* const* d_in, const int* in_sizes, int n_in,
                              void* d_out, int out_size, void* d_ws, size_t ws_size,
                              hipStream_t stream) {
  const float* x   = (const float*)d_in[0];
  const float* eps = (const float*)d_in[1];
  const float* We1 = (const float*)d_in[2];
  const float* be1 = (const float*)d_in[3];
  const float* Wmu = (const float*)d_in[4];
  const float* bmu = (const float*)d_in[5];
  const float* Wls = (const float*)d_in[6];
  const float* bls = (const float*)d_in[7];
  const float* Wd1 = (const float*)d_in[8];
  const float* bd1 = (const float*)d_in[9];
  const float* Wd2 = (const float*)d_in[10];
  const float* bd2 = (const float*)d_in[11];
  float* out = (float*)d_out;

  const int B = 32768, D = 1024, H = 1024, L = 128;

  char* ws = (char*)d_ws;
  size_t off = 0;
  auto alloc = [&](size_t bytes) {
    void* p = ws + off;
    off += (bytes + 255) & ~(size_t)255;
    return p;
  };
  unsigned short* xbit = (unsigned short*)alloc((size_t)B * D / 8);   // 4 MB
  unsigned short* w1t  = (unsigned short*)alloc((size_t)H * D * 2);   // 2 MB  [H][D]
  unsigned short* w2t  = (unsigned short*)alloc((size_t)256 * H * 2); // 0.5MB [256][H]
  unsigned short* wd1t = (unsigned short*)alloc((size_t)H * L * 2);   // .25MB [H][L]
  unsigned short* wd2t = (unsigned short*)alloc((size_t)D * H * 2);   // 2 MB  [D][H]
  unsigned short* h    = (unsigned short*)alloc((size_t)B * H * 2);   // 64 MB
  unsigned short* hd   = h;  // h consumed in-block by latent_fused -> reuse

  TransJob j0{We1, w1t, D, H, 1024};
  TransJob j1{Wmu, w2t, H, L, 1152};
  TransJob j2{Wls, w2t + 128 * H, H, L, 1280};
  TransJob j3{Wd1, wd1t, L, H, 1408};
  TransJob j4{Wd2, wd2t, H, D, 2432};
  // one dispatch: 2432 transpose blocks + 2048 bitpack blocks
  prep_k<<<2432 + 2048, dim3(32, 8), 0, stream>>>(
      j0, j1, j2, j3, j4, x, xbit, B * D / 4, 2048);

  // GEMM1: h = relu(x @ We1 + be1)  [M=32768, N=1024, K=1024], A from xbit,
  // 256 blocks x 2 n-tiles
  gemm256<0, 1, 1><<<256, 512, 0, stream>>>(
      nullptr, w1t, 0, H, D, be1, h, nullptr, xbit);
  // latent: mu/ls -> z (LDS) -> kl -> hd = relu(z @ Wd1 + bd1)
  latent_fused<<<B / 64, 256, 0, stream>>>(
      h, w2t, wd1t, bmu, bls, bd1, eps, hd, out);
  // GEMM4: bernoulli LL accumulated into out [K=1024], split into M-halves
  gemm256<2, 40, 0><<<256, 512, 0, stream>>>(
      hd, wd2t, 0, D, H, bd2, nullptr, out, xbit);
  gemm256<2, 41, 0><<<256, 512, 0, stream>>>(
      hd, wd2t, 16384, D, H, bd2, nullptr, out, xbit);

  (void)in_sizes; (void)n_in; (void)out_size; (void)ws_size;
}

// Round 11
// 430.235 us; speedup vs baseline: 1.2943x; 1.2943x over previous
//
#include <hip/hip_runtime.h>
#include <cstdint>
#include <cstddef>

// VAE forward, fused bf16-MFMA pipeline.
// Sizes fixed: B=32768, INPUT=1024, HIDDEN=1024, LATENT=128.
//
// R15: resubmission of R14 (Round-10 bench was an infra failure --
//     "MI355X container failed twice" -- no kernel signal). Source is
//     unchanged from the R12 configuration measured at 430.1 us.
// R14: full revert of R13 (G1 2-n-tile + G4 M-split + latent counted-vmcnt
//     part-2 regressed 430->557; counters pinned the G1 2-tile variant:
//     VGPR 116->128, WRITE 64->100MB amplification, 1.5M LDS bank
//     conflicts, VALUBusy 37->19).
// R12 (kept): latent 64-row blocks, grid 512, 2 blocks/CU; part-1 BK=32
//     dbuf; part-2 wd1t in 128-col halves.
// R11 (kept): G1 ABIT path (A synthesized from xbit in LDS).
// R10 (kept): merged prep (transposes + bitpack).
// R8 (kept): latent fusion (z in LDS), xbit bitmask epilogue for G4.
// R5 (kept): 256x256, 512 thr/8 waves, BK=64, 8-phase counted-vmcnt.
// R3 (kept): XCD-pinned decode. R2 (kept): XOR-swizzled staging.

typedef __bf16 bf16x8 __attribute__((ext_vector_type(8)));
typedef float f32x4 __attribute__((ext_vector_type(4)));

__device__ __forceinline__ unsigned short f32_to_bf16(float f) {
  unsigned int u = __float_as_uint(f);
  u += 0x7fffu + ((u >> 16) & 1u);   // round-to-nearest-even (finite values)
  return (unsigned short)(u >> 16);
}

// ------------- merged prep: 5 transpose-convert jobs + x bitpack -------------
struct TransJob { const float* in; unsigned short* out; int K, N, blkEnd; };

__global__ void prep_k(TransJob j0, TransJob j1, TransJob j2,
                       TransJob j3, TransJob j4,
                       const float* __restrict__ x,
                       unsigned short* __restrict__ xbit,
                       int n4, int castBlocks) {
  __shared__ float tile[32][33];
  int bid = blockIdx.x;
  int tx = threadIdx.x, ty = threadIdx.y;  // block is 32x8
  if (bid >= j4.blkEnd) {
    // ---- bitpack part: x (exactly {0,1}) -> bitmask ----
    int tid = ty * 32 + tx;
    int stride = castBlocks * 256;
    for (int i = (bid - j4.blkEnd) * 256 + tid; i < n4; i += stride) {
      float4 v = reinterpret_cast<const float4*>(x)[i];
      unsigned int nib = (v.x != 0.f ? 1u : 0u) | (v.y != 0.f ? 2u : 0u) |
                         (v.z != 0.f ? 4u : 0u) | (v.w != 0.f ? 8u : 0u);
      unsigned int n1 = __shfl_down(nib, 1, 64);
      unsigned int n2 = __shfl_down(nib, 2, 64);
      unsigned int n3 = __shfl_down(nib, 3, 64);
      if ((tid & 3) == 0)
        xbit[i >> 2] = (unsigned short)(nib | (n1 << 4) | (n2 << 8) | (n3 << 12));
    }
    return;
  }
  // ---- transpose part: fp32 [K][N] -> bf16 [N][K] ----
  TransJob j; int base;
  if (bid < j0.blkEnd)      { j = j0; base = 0; }
  else if (bid < j1.blkEnd) { j = j1; base = j0.blkEnd; }
  else if (bid < j2.blkEnd) { j = j2; base = j1.blkEnd; }
  else if (bid < j3.blkEnd) { j = j3; base = j2.blkEnd; }
  else                      { j = j4; base = j3.blkEnd; }
  int local = bid - base;
  int gxN = j.N >> 5;
  int n0 = (local % gxN) * 32, k0 = (local / gxN) * 32;
#pragma unroll
  for (int r = 0; r < 32; r += 8)
    tile[ty + r][tx] = j.in[(size_t)(k0 + ty + r) * j.N + n0 + tx];
  __syncthreads();
#pragma unroll
  for (int r = 0; r < 32; r += 8)
    j.out[(size_t)(n0 + ty + r) * j.K + k0 + tx] = f32_to_bf16(tile[tx][ty + r]);
}

// async global->LDS, 16B per lane; LDS dest must be contiguous in lane order
__device__ __forceinline__ void gl_lds16(const unsigned short* g, unsigned short* l) {
  __builtin_amdgcn_global_load_lds(
      (__attribute__((address_space(1))) void*)g,
      (__attribute__((address_space(3))) void*)l, 16, 0, 0);
}

// ---------------- GEMM: C = A[M][K] @ BT[N][K]^T + bias ----------------
// 256x256 tile, 512 threads, 8 waves (2Mx4N), BK=64, 8-phase counted-vmcnt
// pipeline. ABIT=1: A synthesized from xbit bitmask in LDS (A ptr unused).
// EPI 0: relu->bf16. EPI 2: bernoulli LL rowsum via xbit + atomicAdd.
template <int EPI, int TAG, int ABIT>
__global__ __launch_bounds__(512, 2) void gemm256(
    const unsigned short* __restrict__ A, const unsigned short* __restrict__ BT,
    int gx, int N, int K,
    const float* __restrict__ bias0,
    unsigned short* __restrict__ outb, float* __restrict__ outf,
    const unsigned short* __restrict__ xbit) {
  // 128 KB, carved per variant:
  //  ABIT=0: buf b: A = smem+b*32768, B = smem+b*32768+16384
  //  ABIT=1: As = smem (single), Bs[b] = smem+16384+b*16384, xs = smem+49152
  __shared__ __align__(16) unsigned short smem[65536];

  const int tid = threadIdx.x;
  const int lane = tid & 63;
  const int wave = tid >> 6;
  const int wr = wave >> 2;          // 0..1 (M)
  const int wc = wave & 3;           // 0..3 (N)
  const int lm = lane & 15, lq = lane >> 4;
  const int sw = lm & 7;

  const int bid = blockIdx.x;
  const int xcd = bid & 7;
  const int t8 = bid >> 3;
  const int m0 = (xcd + 8 * (t8 / gx)) * 256;
  const int n0 = (t8 % gx) * 256;
  const int NT = K >> 6;

  unsigned short* const smemp = smem;
  auto Abuf = [&](int b) -> unsigned short* {
    return ABIT ? smemp : smemp + b * 32768;
  };
  auto Bbuf = [&](int b) -> unsigned short* {
    return ABIT ? smemp + 16384 + b * 16384 : smemp + b * 32768 + 16384;
  };

  // Half-stage regions (16 KB each = 2 chunks/thread):
  //  A1: rows {0-63,128-191}   A2: rows {64-127,192-255}
  //  B1: rows {0-31,64-95,128-159,192-223}   B2: B1+32
  const unsigned short* gpA[2];
  const unsigned short* gpB[2];
  int loA[2], loB[2], xaddr[2];
#pragma unroll
  for (int r = 0; r < 2; ++r) {
    int c = tid + 512 * r, rl = c >> 3, q8 = c & 7;
    int rowA = (rl & 63) + ((rl >> 6) << 7);   // A1 row
    int rowB = (rl & 31) + ((rl >> 5) << 6);   // B1 row
    int qgA = q8 ^ (rowA & 7);
    gpA[r] = A + (size_t)(m0 + rowA) * K + qgA * 8;
    gpB[r] = BT + (size_t)(n0 + rowB) * K + (q8 ^ (rowB & 7)) * 8;
    loA[r] = rowA * 64 + q8 * 8;
    loB[r] = rowB * 64 + q8 * 8;
    xaddr[r] = rowA * 128 + qgA;               // xs byte addr (tile 0)
  }

  auto stage = [&](int kind, int buf, int kt) {
#pragma unroll
    for (int r = 0; r < 2; ++r) {
      if (kind == 0)      { if (!ABIT) gl_lds16(gpA[r] + kt * 64,          Abuf(buf) + loA[r]); }
      else if (kind == 3) { if (!ABIT) gl_lds16(gpA[r] + 64 * K + kt * 64, Abuf(buf) + loA[r] + 4096); }
      else if (kind == 1) gl_lds16(gpB[r] + kt * 64,          Bbuf(buf) + loB[r]);
      else                gl_lds16(gpB[r] + 32 * K + kt * 64, Bbuf(buf) + loB[r] + 2048);
    }
  };

  // bits -> bf16 expansion of A for K-tile t (ABIT only).
  auto expandA = [&](int t) {
    const unsigned char* xsb = reinterpret_cast<const unsigned char*>(smemp + 49152);
    unsigned short* As = smemp;
#pragma unroll
    for (int r = 0; r < 2; ++r) {
#pragma unroll
      for (int h = 0; h < 2; ++h) {   // h=0: A1 row; h=1: A2 = +64 rows
        unsigned int b = xsb[xaddr[r] + h * 8192 + 8 * t];
        unsigned int o0 = ((b & 1u)        ? 0x3F80u : 0u) | ((b & 2u)   ? 0x3F800000u : 0u);
        unsigned int o1 = (((b >> 2) & 1u) ? 0x3F80u : 0u) | ((b & 8u)   ? 0x3F800000u : 0u);
        unsigned int o2 = (((b >> 4) & 1u) ? 0x3F80u : 0u) | ((b & 32u)  ? 0x3F800000u : 0u);
        unsigned int o3 = (((b >> 6) & 1u) ? 0x3F80u : 0u) | ((b & 128u) ? 0x3F800000u : 0u);
        *reinterpret_cast<uint4*>(As + loA[r] + h * 4096) = make_uint4(o0, o1, o2, o3);
      }
    }
  };

  // ---- prologue ----
  if (ABIT) {
    const unsigned short* xp = xbit + (size_t)m0 * 64;   // 32 KB panel, contiguous
    unsigned short* xs = smemp + 49152;
#pragma unroll
    for (int i = 0; i < 4; ++i)
      gl_lds16(xp + (tid + 512 * i) * 8, xs + (tid + 512 * i) * 8);
    stage(1, 0, 0); stage(2, 0, 0);          // B(t0)
    stage(1, 1, 1); stage(2, 1, 1);          // B(t1)
    asm volatile("s_waitcnt vmcnt(8)" ::: "memory");   // xs landed
    expandA(0);
    asm volatile("s_waitcnt vmcnt(4) lgkmcnt(0)" ::: "memory");  // B(t0)+expand done
    __builtin_amdgcn_s_barrier();
  } else {
    stage(0, 0, 0); stage(1, 0, 0); stage(2, 0, 0); stage(3, 0, 0);
    stage(0, 1, 1); stage(1, 1, 1); stage(2, 1, 1);
    asm volatile("s_waitcnt vmcnt(6)" ::: "memory");
    __builtin_amdgcn_s_barrier();
  }

  f32x4 acc[8][4] = {};

  const int aRow = (wr * 128 + lm) * 64;
  const int bRow = (wc * 64 + lm) * 64;
  const int c0 = ((0 | lq) ^ sw) * 8;
  const int c1 = ((4 | lq) ^ sw) * 8;

  for (int t = 0; t < NT; ++t) {
    const int b = t & 1;
    const unsigned short* Ab = Abuf(b);
    const unsigned short* Bb = Bbuf(b);
    bf16x8 af[4][2], bf1[2][2], bf2[2][2];

    // ---- P1: af-low + bf1 reads; stage A2(t+1) [non-ABIT] ----
#pragma unroll
    for (int i = 0; i < 4; ++i) {
      af[i][0] = *reinterpret_cast<const bf16x8*>(Ab + aRow + i * 1024 + c0);
      af[i][1] = *reinterpret_cast<const bf16x8*>(Ab + aRow + i * 1024 + c1);
    }
#pragma unroll
    for (int j = 0; j < 2; ++j) {
      bf1[j][0] = *reinterpret_cast<const bf16x8*>(Bb + bRow + j * 1024 + c0);
      bf1[j][1] = *reinterpret_cast<const bf16x8*>(Bb + bRow + j * 1024 + c1);
    }
    if (!ABIT && t + 1 < NT) stage(3, (t + 1) & 1, t + 1);
    __builtin_amdgcn_s_barrier();
    asm volatile("s_waitcnt lgkmcnt(0)" ::: "memory");
    __builtin_amdgcn_sched_barrier(0);
    __builtin_amdgcn_s_setprio(1);
#pragma unroll
    for (int s = 0; s < 2; ++s)
#pragma unroll
      for (int i = 0; i < 4; ++i)
#pragma unroll
        for (int j = 0; j < 2; ++j)
          acc[i][j] = __builtin_amdgcn_mfma_f32_16x16x32_bf16(af[i][s], bf1[j][s], acc[i][j], 0, 0, 0);
    __builtin_amdgcn_s_setprio(0);
    __builtin_amdgcn_s_barrier();

    // ---- P2: bf2 reads; stage B1(t+2) [ABIT] / A1(t+2) [non-ABIT] ----
#pragma unroll
    for (int j = 0; j < 2; ++j) {
      bf2[j][0] = *reinterpret_cast<const bf16x8*>(Bb + bRow + (j + 2) * 1024 + c0);
      bf2[j][1] = *reinterpret_cast<const bf16x8*>(Bb + bRow + (j + 2) * 1024 + c1);
    }
    if (t + 2 < NT) stage(ABIT ? 1 : 0, b, t + 2);
    __builtin_amdgcn_s_barrier();
    asm volatile("s_waitcnt lgkmcnt(0)" ::: "memory");
    __builtin_amdgcn_sched_barrier(0);
    __builtin_amdgcn_s_setprio(1);
#pragma unroll
    for (int s = 0; s < 2; ++s)
#pragma unroll
      for (int i = 0; i < 4; ++i)
#pragma unroll
        for (int j = 0; j < 2; ++j)
          acc[i][j + 2] = __builtin_amdgcn_mfma_f32_16x16x32_bf16(af[i][s], bf2[j][s], acc[i][j + 2], 0, 0, 0);
    __builtin_amdgcn_s_setprio(0);
    __builtin_amdgcn_s_barrier();

    // ---- P3: af-high reads; stage B2(t+2) [ABIT] / B1(t+2) [non-ABIT] ----
#pragma unroll
    for (int i = 0; i < 4; ++i) {
      af[i][0] = *reinterpret_cast<const bf16x8*>(Ab + aRow + (64 + i * 16) * 64 + c0);
      af[i][1] = *reinterpret_cast<const bf16x8*>(Ab + aRow + (64 + i * 16) * 64 + c1);
    }
    if (t + 2 < NT) stage(ABIT ? 2 : 1, b, t + 2);
    __builtin_amdgcn_s_barrier();
    asm volatile("s_waitcnt lgkmcnt(0)" ::: "memory");
    __builtin_amdgcn_sched_barrier(0);
    __builtin_amdgcn_s_setprio(1);
#pragma unroll
    for (int s = 0; s < 2; ++s)
#pragma unroll
      for (int i = 0; i < 4; ++i)
#pragma unroll
        for (int j = 0; j < 2; ++j)
          acc[i + 4][j] = __builtin_amdgcn_mfma_f32_16x16x32_bf16(af[i][s], bf1[j][s], acc[i + 4][j], 0, 0, 0);
    __builtin_amdgcn_s_setprio(0);
    __builtin_amdgcn_s_barrier();

    // ---- P4: expand A(t+1) [ABIT] / stage B2(t+2) [non-ABIT]; MFMA C4 ----
    if (ABIT) { if (t + 1 < NT) expandA(t + 1); }
    else      { if (t + 2 < NT) stage(2, b, t + 2); }
    __builtin_amdgcn_s_barrier();
    __builtin_amdgcn_s_setprio(1);
#pragma unroll
    for (int s = 0; s < 2; ++s)
#pragma unroll
      for (int i = 0; i < 4; ++i)
#pragma unroll
        for (int j = 0; j < 2; ++j)
          acc[i + 4][j + 2] = __builtin_amdgcn_mfma_f32_16x16x32_bf16(af[i][s], bf2[j][s], acc[i + 4][j + 2], 0, 0, 0);
    __builtin_amdgcn_s_setprio(0);
    if (ABIT) {
      if (t + 2 < NT) { asm volatile("s_waitcnt vmcnt(4) lgkmcnt(0)" ::: "memory"); }
      else            { asm volatile("s_waitcnt vmcnt(0) lgkmcnt(0)" ::: "memory"); }
    } else {
      if (t + 2 < NT)      { asm volatile("s_waitcnt vmcnt(6)" ::: "memory"); }
      else if (t + 1 < NT) { asm volatile("s_waitcnt vmcnt(0)" ::: "memory"); }
    }
    __builtin_amdgcn_s_barrier();
  }

  if (EPI == 0) {
#pragma unroll
    for (int i = 0; i < 8; ++i)
#pragma unroll
      for (int j = 0; j < 4; ++j) {
        int col = n0 + wc * 64 + j * 16 + lm;
        float bias = bias0[col];
#pragma unroll
        for (int r = 0; r < 4; ++r) {
          int row = m0 + wr * 128 + i * 16 + lq * 4 + r;
          float v = acc[i][j][r] + bias;
          outb[(size_t)row * N + col] = f32_to_bf16(fmaxf(v, 0.f));
        }
      }
  } else {
    const int wpr = N >> 4;   // bitmask words per row
#pragma unroll
    for (int i = 0; i < 8; ++i) {
      float rs[4] = {0.f, 0.f, 0.f, 0.f};
#pragma unroll
      for (int j = 0; j < 4; ++j) {
        int col = n0 + wc * 64 + j * 16 + lm;
        float bias = bias0[col];
        int w16 = (col >> 4);
#pragma unroll
        for (int r = 0; r < 4; ++r) {
          int row = m0 + wr * 128 + i * 16 + lq * 4 + r;
          float l = acc[i][j][r] + bias;
          unsigned short mask = xbit[(size_t)row * wpr + w16];  // broadcast
          float tt = ((mask >> lm) & 1) ? -l : l;
          float sp = fmaxf(tt, 0.f) + __logf(1.f + __expf(-fabsf(tt)));
          rs[r] -= sp;
        }
      }
#pragma unroll
      for (int off = 1; off < 16; off <<= 1)
#pragma unroll
        for (int r = 0; r < 4; ++r) rs[r] += __shfl_xor(rs[r], off, 64);
      if (lm == 0) {
#pragma unroll
        for (int r = 0; r < 4; ++r)
          atomicAdd(&outf[m0 + wr * 128 + i * 16 + lq * 4 + r], rs[r]);
      }
    }
  }
}

// -------- latent_fused: S2 = h @ w2t^T (N=256) -> z/kl -> hd = relu(z@Wd1+bd1) --------
// One block per 64 batch rows (grid 512), 256 thr / 4 waves, LDS 56 KB ->
// 2 blocks/CU (2 waves/SIMD from different blocks). Part 1 BK=32 dbuf, one
// __syncthreads per K-tile; wave = 16 rows x 256 cols (acc[16], mu at
// n-tile j<8 / ls at j+8 in the same lane). Part 2: wd1t staged in 128-col
// halves (Bs2 32 KB overlays dead part-1 buffers), K=128 MFMA.
__global__ __launch_bounds__(256, 2) void latent_fused(
    const unsigned short* A,                  // h [B][1024] (also hd output)
    const unsigned short* __restrict__ BT,    // w2t [256][1024]
    const unsigned short* __restrict__ WD1,   // wd1t [1024][128]
    const float* __restrict__ bmu, const float* __restrict__ bls,
    const float* __restrict__ bd1,
    const float* __restrict__ eps,            // [B][128]
    unsigned short* hd,                       // [B][1024] (= h buffer)
    float* __restrict__ out) {
  __shared__ __align__(16) unsigned short smem[28672];   // 56 KB
  unsigned short* As0 = smem;              // [64*32]   0..2047
  unsigned short* As1 = smem + 2048;       // [64*32]   2048..4095
  unsigned short* Bs0 = smem + 4096;       // [256*32]  4096..12287
  unsigned short* Bs1 = smem + 12288;      // [256*32]  12288..20479
  unsigned short* zs  = smem + 20480;      // [64*128]  20480..28671
  unsigned short* Bs2 = smem;              // [128*128] part 2 (overlays As+Bs)

  const int K = 1024;
  const int tid = threadIdx.x;
  const int lane = tid & 63;
  const int wave = tid >> 6;
  const int m0 = blockIdx.x * 64;
  const int lm = lane & 15, lq = lane >> 4;
  const int sw2 = (lm >> 1) & 3;           // BK=32 read swizzle (R7 pattern)

  // ---- part 1 staging: A 256 chunks (1/thread), B 1024 chunks (4/thread)
  const unsigned short* agp;
  const unsigned short* bgp[4];
  {
    int row = tid >> 2, q = tid & 3;
    agp = A + (size_t)(m0 + row) * K + (q ^ ((row >> 1) & 3)) * 8;
  }
#pragma unroll
  for (int r = 0; r < 4; ++r) {
    int c = tid + 256 * r;
    int row = c >> 2, q = c & 3;
    bgp[r] = BT + (size_t)row * K + (q ^ ((row >> 1) & 3)) * 8;
  }

  auto stage1 = [&](int buf, int kt) {
    gl_lds16(agp + kt, (buf ? As1 : As0) + tid * 8);
    unsigned short* Bd = buf ? Bs1 : Bs0;
#pragma unroll
    for (int r = 0; r < 4; ++r) gl_lds16(bgp[r] + kt, Bd + (tid + 256 * r) * 8);
  };

  f32x4 acc[16] = {};

  stage1(0, 0);
  __syncthreads();

  const int aOff = (wave * 16 + lm) * 32 + (lq ^ sw2) * 8;
  for (int t = 0; t < 32; ++t) {
    const int cur = t & 1;
    if (t + 1 < 32) stage1(cur ^ 1, (t + 1) * 32);   // full-tile window
    const unsigned short* Ab = cur ? As1 : As0;
    const unsigned short* Bb = cur ? Bs1 : Bs0;
    bf16x8 af = *reinterpret_cast<const bf16x8*>(Ab + aOff);
#pragma unroll
    for (int j = 0; j < 16; ++j) {
      bf16x8 b = *reinterpret_cast<const bf16x8*>(Bb + (j * 16 + lm) * 32 + (lq ^ sw2) * 8);
      acc[j] = __builtin_amdgcn_mfma_f32_16x16x32_bf16(af, b, acc[j], 0, 0, 0);
    }
    __syncthreads();   // implicit vmcnt(0): stage had a full tile to land
  }

  // part 2 staging: wd1t half [128 rows][128 k] -> Bs2; row = 256 B = 16
  // chunks; slot s of row r holds global chunk s ^ (r&7). 8 chunks/thread.
  auto stage2 = [&](int hh) {
#pragma unroll
    for (int ri = 0; ri < 8; ++ri) {
      int c = tid + 256 * ri;
      int row = c >> 4, slot = c & 15;
      int gc = slot ^ (row & 7);
      gl_lds16(WD1 + (size_t)(hh * 128 + row) * 128 + gc * 8, Bs2 + c * 8);
    }
  };
  stage2(0);   // overlays dead part-1 buffers; overlaps the z/kl epilogue

  // ---- part 1 epilogue: z -> zs (swizzled), kl -> out ----
  {
    float kl[4] = {0.f, 0.f, 0.f, 0.f};
#pragma unroll
    for (int j = 0; j < 8; ++j) {
      int dim = j * 16 + lm;
      float bm = bmu[dim], bl = bls[dim];
#pragma unroll
      for (int r = 0; r < 4; ++r) {
        int rowl = wave * 16 + lq * 4 + r;                  // local row
        float mu = acc[j][r] + bm;
        float ls = acc[j + 8][r] + bl;
        float e = eps[(size_t)(m0 + rowl) * 128 + dim];
        float zv = fmaf(__expf(ls), e, mu);
        int chunk = (dim >> 3);
        int slot = chunk ^ (rowl & 7);
        zs[rowl * 128 + slot * 8 + (lm & 7)] = f32_to_bf16(zv);
        kl[r] += 0.5f * (__expf(2.f * ls) + mu * mu - 2.f * ls - 1.f);
      }
    }
#pragma unroll
    for (int off = 1; off < 16; off <<= 1)
#pragma unroll
      for (int r = 0; r < 4; ++r) kl[r] += __shfl_xor(kl[r], off, 64);
    if (lm == 0) {
#pragma unroll
      for (int r = 0; r < 4; ++r)
        out[m0 + wave * 16 + lq * 4 + r] = -kl[r];
    }
  }

  // ---- part 2: hd = relu(z @ wd1t^T + bd1), 8 half-tiles of 128 cols ----
  for (int hh = 0; hh < 8; ++hh) {
    asm volatile("s_waitcnt vmcnt(0)" ::: "memory");
    __syncthreads();                       // Bs2[hh] staged; zs visible (hh=0)
    f32x4 acc2[8] = {};
#pragma unroll
    for (int ks = 0; ks < 4; ++ks) {
      const int cks = (ks * 4 + lq) ^ (lm & 7);
      bf16x8 a0 = *reinterpret_cast<const bf16x8*>(zs + (wave * 16 + lm) * 128 + cks * 8);
#pragma unroll
      for (int j = 0; j < 8; ++j) {
        bf16x8 b = *reinterpret_cast<const bf16x8*>(Bs2 + (j * 16 + lm) * 128 + cks * 8);
        acc2[j] = __builtin_amdgcn_mfma_f32_16x16x32_bf16(a0, b, acc2[j], 0, 0, 0);
      }
    }
    __syncthreads();                       // all waves done reading Bs2
    if (hh + 1 < 8) stage2(hh + 1);        // latency hidden under hd writes
#pragma unroll
    for (int j = 0; j < 8; ++j) {
      int col = hh * 128 + j * 16 + lm;
      float bias = bd1[col];
#pragma unroll
      for (int r = 0; r < 4; ++r) {
        int row = m0 + wave * 16 + lq * 4 + r;
        float v = acc2[j][r] + bias;
        hd[(size_t)row * 1024 + col] = f32_to_bf16(fmaxf(v, 0.f));
      }
    }
  }
}

extern "C" void kernel_launch(void* const* d_in, const int* in_sizes, int n_in,
                              void* d_out, int out_size, void* d_ws, size_t ws_size,
                              hipStream_t stream) {
  const float* x   = (const float*)d_in[0];
  const float* eps = (const float*)d_in[1];
  const float* We1 = (const float*)d_in[2];
  const float* be1 = (const float*)d_in[3];
  const float* Wmu = (const float*)d_in[4];
  const float* bmu = (const float*)d_in[5];
  const float* Wls = (const float*)d_in[6];
  const float* bls = (const float*)d_in[7];
  const float* Wd1 = (const float*)d_in[8];
  const float* bd1 = (const float*)d_in[9];
  const float* Wd2 = (const float*)d_in[10];
  const float* bd2 = (const float*)d_in[11];
  float* out = (float*)d_out;

  const int B = 32768, D = 1024, H = 1024, L = 128;

  char* ws = (char*)d_ws;
  size_t off = 0;
  auto alloc = [&](size_t bytes) {
    void* p = ws + off;
    off += (bytes + 255) & ~(size_t)255;
    return p;
  };
  unsigned short* xbit = (unsigned short*)alloc((size_t)B * D / 8);   // 4 MB
  unsigned short* w1t  = (unsigned short*)alloc((size_t)H * D * 2);   // 2 MB  [H][D]
  unsigned short* w2t  = (unsigned short*)alloc((size_t)256 * H * 2); // 0.5MB [256][H]
  unsigned short* wd1t = (unsigned short*)alloc((size_t)H * L * 2);   // .25MB [H][L]
  unsigned short* wd2t = (unsigned short*)alloc((size_t)D * H * 2);   // 2 MB  [D][H]
  unsigned short* h    = (unsigned short*)alloc((size_t)B * H * 2);   // 64 MB
  unsigned short* hd   = h;  // h consumed in-block by latent_fused -> reuse

  TransJob j0{We1, w1t, D, H, 1024};
  TransJob j1{Wmu, w2t, H, L, 1152};
  TransJob j2{Wls, w2t + 128 * H, H, L, 1280};
  TransJob j3{Wd1, wd1t, L, H, 1408};
  TransJob j4{Wd2, wd2t, H, D, 2432};
  // one dispatch: 2432 transpose blocks + 2048 bitpack blocks
  prep_k<<<2432 + 2048, dim3(32, 8), 0, stream>>>(
      j0, j1, j2, j3, j4, x, xbit, B * D / 4, 2048);

  // GEMM1: h = relu(x @ We1 + be1)   [M=32768, N=1024, K=1024], A from xbit
  gemm256<0, 1, 1><<<512, 512, 0, stream>>>(
      nullptr, w1t, 4, H, D, be1, h, nullptr, xbit);
  // latent: mu/ls -> z (LDS) -> kl -> hd = relu(z @ Wd1 + bd1)
  latent_fused<<<B / 64, 256, 0, stream>>>(
      h, w2t, wd1t, bmu, bls, bd1, eps, hd, out);
  // GEMM4: bernoulli log-likelihood accumulated into out [K=1024] (control)
  gemm256<2, 4, 0><<<512, 512, 0, stream>>>(
      hd, wd2t, 4, D, H, bd2, nullptr, out, xbit);

  (void)in_sizes; (void)n_in; (void)out_size; (void)ws_size;
}

// Round 12
// 429.375 us; speedup vs baseline: 1.2969x; 1.0020x over previous
//
#include <hip/hip_runtime.h>
#include <cstdint>
#include <cstddef>

// VAE forward, fused bf16-MFMA pipeline.
// Sizes fixed: B=32768, INPUT=1024, HIDDEN=1024, LATENT=128.
//
// R16: latent part-1 wave re-decomposition. Old: wave = 16 rows x 256
//     cols -> 1 A-read + 16 B-reads per 16 MFMA; per-CU LDS pipe ~1630
//     cyc/K-tile vs 620 MFMA -> LDS-read-bound (explains why R12's
//     occupancy fix under-delivered). New: wave = 64 rows x 64 cols with
//     col-tiles {2w,2w+1, 2w+8,2w+9} -> 4 A + 4 B reads per 16 MFMA
//     (68 -> 32 reads/block/K-tile, pipe balanced) AND mu/ls stay paired
//     in-lane (acc[i][j] = mu, acc[i][j+2] = ls, same dim). kl rowsum now
//     crosses waves: 1 KB LDS klbuf + barrier + 64-thread final sum.
//     Part-2, gemm256, prep unchanged from the confirmed 430.1 baseline.
// R15/R14: revert of R13, confirmed at 430.2 (G4 ~100us, FETCH 49.7MB,
//     conflicts 0, VGPR 116 -- all predicted signatures matched).
// R12 (kept): latent 64-row blocks, grid 512, 2 blocks/CU; part-1 BK=32
//     dbuf; part-2 wd1t in 128-col halves.
// R11 (kept): G1 ABIT path (A synthesized from xbit in LDS).
// R10 (kept): merged prep (transposes + bitpack).
// R8 (kept): latent fusion (z in LDS), xbit bitmask epilogue for G4.
// R5 (kept): 256x256, 512 thr/8 waves, BK=64, 8-phase counted-vmcnt.
// R3 (kept): XCD-pinned decode. R2 (kept): XOR-swizzled staging.

typedef __bf16 bf16x8 __attribute__((ext_vector_type(8)));
typedef float f32x4 __attribute__((ext_vector_type(4)));

__device__ __forceinline__ unsigned short f32_to_bf16(float f) {
  unsigned int u = __float_as_uint(f);
  u += 0x7fffu + ((u >> 16) & 1u);   // round-to-nearest-even (finite values)
  return (unsigned short)(u >> 16);
}

// ------------- merged prep: 5 transpose-convert jobs + x bitpack -------------
struct TransJob { const float* in; unsigned short* out; int K, N, blkEnd; };

__global__ void prep_k(TransJob j0, TransJob j1, TransJob j2,
                       TransJob j3, TransJob j4,
                       const float* __restrict__ x,
                       unsigned short* __restrict__ xbit,
                       int n4, int castBlocks) {
  __shared__ float tile[32][33];
  int bid = blockIdx.x;
  int tx = threadIdx.x, ty = threadIdx.y;  // block is 32x8
  if (bid >= j4.blkEnd) {
    // ---- bitpack part: x (exactly {0,1}) -> bitmask ----
    int tid = ty * 32 + tx;
    int stride = castBlocks * 256;
    for (int i = (bid - j4.blkEnd) * 256 + tid; i < n4; i += stride) {
      float4 v = reinterpret_cast<const float4*>(x)[i];
      unsigned int nib = (v.x != 0.f ? 1u : 0u) | (v.y != 0.f ? 2u : 0u) |
                         (v.z != 0.f ? 4u : 0u) | (v.w != 0.f ? 8u : 0u);
      unsigned int n1 = __shfl_down(nib, 1, 64);
      unsigned int n2 = __shfl_down(nib, 2, 64);
      unsigned int n3 = __shfl_down(nib, 3, 64);
      if ((tid & 3) == 0)
        xbit[i >> 2] = (unsigned short)(nib | (n1 << 4) | (n2 << 8) | (n3 << 12));
    }
    return;
  }
  // ---- transpose part: fp32 [K][N] -> bf16 [N][K] ----
  TransJob j; int base;
  if (bid < j0.blkEnd)      { j = j0; base = 0; }
  else if (bid < j1.blkEnd) { j = j1; base = j0.blkEnd; }
  else if (bid < j2.blkEnd) { j = j2; base = j1.blkEnd; }
  else if (bid < j3.blkEnd) { j = j3; base = j2.blkEnd; }
  else                      { j = j4; base = j3.blkEnd; }
  int local = bid - base;
  int gxN = j.N >> 5;
  int n0 = (local % gxN) * 32, k0 = (local / gxN) * 32;
#pragma unroll
  for (int r = 0; r < 32; r += 8)
    tile[ty + r][tx] = j.in[(size_t)(k0 + ty + r) * j.N + n0 + tx];
  __syncthreads();
#pragma unroll
  for (int r = 0; r < 32; r += 8)
    j.out[(size_t)(n0 + ty + r) * j.K + k0 + tx] = f32_to_bf16(tile[tx][ty + r]);
}

// async global->LDS, 16B per lane; LDS dest must be contiguous in lane order
__device__ __forceinline__ void gl_lds16(const unsigned short* g, unsigned short* l) {
  __builtin_amdgcn_global_load_lds(
      (__attribute__((address_space(1))) void*)g,
      (__attribute__((address_space(3))) void*)l, 16, 0, 0);
}

// ---------------- GEMM: C = A[M][K] @ BT[N][K]^T + bias ----------------
// 256x256 tile, 512 threads, 8 waves (2Mx4N), BK=64, 8-phase counted-vmcnt
// pipeline. ABIT=1: A synthesized from xbit bitmask in LDS (A ptr unused).
// EPI 0: relu->bf16. EPI 2: bernoulli LL rowsum via xbit + atomicAdd.
template <int EPI, int TAG, int ABIT>
__global__ __launch_bounds__(512, 2) void gemm256(
    const unsigned short* __restrict__ A, const unsigned short* __restrict__ BT,
    int gx, int N, int K,
    const float* __restrict__ bias0,
    unsigned short* __restrict__ outb, float* __restrict__ outf,
    const unsigned short* __restrict__ xbit) {
  // 128 KB, carved per variant:
  //  ABIT=0: buf b: A = smem+b*32768, B = smem+b*32768+16384
  //  ABIT=1: As = smem (single), Bs[b] = smem+16384+b*16384, xs = smem+49152
  __shared__ __align__(16) unsigned short smem[65536];

  const int tid = threadIdx.x;
  const int lane = tid & 63;
  const int wave = tid >> 6;
  const int wr = wave >> 2;          // 0..1 (M)
  const int wc = wave & 3;           // 0..3 (N)
  const int lm = lane & 15, lq = lane >> 4;
  const int sw = lm & 7;

  const int bid = blockIdx.x;
  const int xcd = bid & 7;
  const int t8 = bid >> 3;
  const int m0 = (xcd + 8 * (t8 / gx)) * 256;
  const int n0 = (t8 % gx) * 256;
  const int NT = K >> 6;

  unsigned short* const smemp = smem;
  auto Abuf = [&](int b) -> unsigned short* {
    return ABIT ? smemp : smemp + b * 32768;
  };
  auto Bbuf = [&](int b) -> unsigned short* {
    return ABIT ? smemp + 16384 + b * 16384 : smemp + b * 32768 + 16384;
  };

  // Half-stage regions (16 KB each = 2 chunks/thread):
  //  A1: rows {0-63,128-191}   A2: rows {64-127,192-255}
  //  B1: rows {0-31,64-95,128-159,192-223}   B2: B1+32
  const unsigned short* gpA[2];
  const unsigned short* gpB[2];
  int loA[2], loB[2], xaddr[2];
#pragma unroll
  for (int r = 0; r < 2; ++r) {
    int c = tid + 512 * r, rl = c >> 3, q8 = c & 7;
    int rowA = (rl & 63) + ((rl >> 6) << 7);   // A1 row
    int rowB = (rl & 31) + ((rl >> 5) << 6);   // B1 row
    int qgA = q8 ^ (rowA & 7);
    gpA[r] = A + (size_t)(m0 + rowA) * K + qgA * 8;
    gpB[r] = BT + (size_t)(n0 + rowB) * K + (q8 ^ (rowB & 7)) * 8;
    loA[r] = rowA * 64 + q8 * 8;
    loB[r] = rowB * 64 + q8 * 8;
    xaddr[r] = rowA * 128 + qgA;               // xs byte addr (tile 0)
  }

  auto stage = [&](int kind, int buf, int kt) {
#pragma unroll
    for (int r = 0; r < 2; ++r) {
      if (kind == 0)      { if (!ABIT) gl_lds16(gpA[r] + kt * 64,          Abuf(buf) + loA[r]); }
      else if (kind == 3) { if (!ABIT) gl_lds16(gpA[r] + 64 * K + kt * 64, Abuf(buf) + loA[r] + 4096); }
      else if (kind == 1) gl_lds16(gpB[r] + kt * 64,          Bbuf(buf) + loB[r]);
      else                gl_lds16(gpB[r] + 32 * K + kt * 64, Bbuf(buf) + loB[r] + 2048);
    }
  };

  // bits -> bf16 expansion of A for K-tile t (ABIT only).
  auto expandA = [&](int t) {
    const unsigned char* xsb = reinterpret_cast<const unsigned char*>(smemp + 49152);
    unsigned short* As = smemp;
#pragma unroll
    for (int r = 0; r < 2; ++r) {
#pragma unroll
      for (int h = 0; h < 2; ++h) {   // h=0: A1 row; h=1: A2 = +64 rows
        unsigned int b = xsb[xaddr[r] + h * 8192 + 8 * t];
        unsigned int o0 = ((b & 1u)        ? 0x3F80u : 0u) | ((b & 2u)   ? 0x3F800000u : 0u);
        unsigned int o1 = (((b >> 2) & 1u) ? 0x3F80u : 0u) | ((b & 8u)   ? 0x3F800000u : 0u);
        unsigned int o2 = (((b >> 4) & 1u) ? 0x3F80u : 0u) | ((b & 32u)  ? 0x3F800000u : 0u);
        unsigned int o3 = (((b >> 6) & 1u) ? 0x3F80u : 0u) | ((b & 128u) ? 0x3F800000u : 0u);
        *reinterpret_cast<uint4*>(As + loA[r] + h * 4096) = make_uint4(o0, o1, o2, o3);
      }
    }
  };

  // ---- prologue ----
  if (ABIT) {
    const unsigned short* xp = xbit + (size_t)m0 * 64;   // 32 KB panel, contiguous
    unsigned short* xs = smemp + 49152;
#pragma unroll
    for (int i = 0; i < 4; ++i)
      gl_lds16(xp + (tid + 512 * i) * 8, xs + (tid + 512 * i) * 8);
    stage(1, 0, 0); stage(2, 0, 0);          // B(t0)
    stage(1, 1, 1); stage(2, 1, 1);          // B(t1)
    asm volatile("s_waitcnt vmcnt(8)" ::: "memory");   // xs landed
    expandA(0);
    asm volatile("s_waitcnt vmcnt(4) lgkmcnt(0)" ::: "memory");  // B(t0)+expand done
    __builtin_amdgcn_s_barrier();
  } else {
    stage(0, 0, 0); stage(1, 0, 0); stage(2, 0, 0); stage(3, 0, 0);
    stage(0, 1, 1); stage(1, 1, 1); stage(2, 1, 1);
    asm volatile("s_waitcnt vmcnt(6)" ::: "memory");
    __builtin_amdgcn_s_barrier();
  }

  f32x4 acc[8][4] = {};

  const int aRow = (wr * 128 + lm) * 64;
  const int bRow = (wc * 64 + lm) * 64;
  const int c0 = ((0 | lq) ^ sw) * 8;
  const int c1 = ((4 | lq) ^ sw) * 8;

  for (int t = 0; t < NT; ++t) {
    const int b = t & 1;
    const unsigned short* Ab = Abuf(b);
    const unsigned short* Bb = Bbuf(b);
    bf16x8 af[4][2], bf1[2][2], bf2[2][2];

    // ---- P1: af-low + bf1 reads; stage A2(t+1) [non-ABIT] ----
#pragma unroll
    for (int i = 0; i < 4; ++i) {
      af[i][0] = *reinterpret_cast<const bf16x8*>(Ab + aRow + i * 1024 + c0);
      af[i][1] = *reinterpret_cast<const bf16x8*>(Ab + aRow + i * 1024 + c1);
    }
#pragma unroll
    for (int j = 0; j < 2; ++j) {
      bf1[j][0] = *reinterpret_cast<const bf16x8*>(Bb + bRow + j * 1024 + c0);
      bf1[j][1] = *reinterpret_cast<const bf16x8*>(Bb + bRow + j * 1024 + c1);
    }
    if (!ABIT && t + 1 < NT) stage(3, (t + 1) & 1, t + 1);
    __builtin_amdgcn_s_barrier();
    asm volatile("s_waitcnt lgkmcnt(0)" ::: "memory");
    __builtin_amdgcn_sched_barrier(0);
    __builtin_amdgcn_s_setprio(1);
#pragma unroll
    for (int s = 0; s < 2; ++s)
#pragma unroll
      for (int i = 0; i < 4; ++i)
#pragma unroll
        for (int j = 0; j < 2; ++j)
          acc[i][j] = __builtin_amdgcn_mfma_f32_16x16x32_bf16(af[i][s], bf1[j][s], acc[i][j], 0, 0, 0);
    __builtin_amdgcn_s_setprio(0);
    __builtin_amdgcn_s_barrier();

    // ---- P2: bf2 reads; stage B1(t+2) [ABIT] / A1(t+2) [non-ABIT] ----
#pragma unroll
    for (int j = 0; j < 2; ++j) {
      bf2[j][0] = *reinterpret_cast<const bf16x8*>(Bb + bRow + (j + 2) * 1024 + c0);
      bf2[j][1] = *reinterpret_cast<const bf16x8*>(Bb + bRow + (j + 2) * 1024 + c1);
    }
    if (t + 2 < NT) stage(ABIT ? 1 : 0, b, t + 2);
    __builtin_amdgcn_s_barrier();
    asm volatile("s_waitcnt lgkmcnt(0)" ::: "memory");
    __builtin_amdgcn_sched_barrier(0);
    __builtin_amdgcn_s_setprio(1);
#pragma unroll
    for (int s = 0; s < 2; ++s)
#pragma unroll
      for (int i = 0; i < 4; ++i)
#pragma unroll
        for (int j = 0; j < 2; ++j)
          acc[i][j + 2] = __builtin_amdgcn_mfma_f32_16x16x32_bf16(af[i][s], bf2[j][s], acc[i][j + 2], 0, 0, 0);
    __builtin_amdgcn_s_setprio(0);
    __builtin_amdgcn_s_barrier();

    // ---- P3: af-high reads; stage B2(t+2) [ABIT] / B1(t+2) [non-ABIT] ----
#pragma unroll
    for (int i = 0; i < 4; ++i) {
      af[i][0] = *reinterpret_cast<const bf16x8*>(Ab + aRow + (64 + i * 16) * 64 + c0);
      af[i][1] = *reinterpret_cast<const bf16x8*>(Ab + aRow + (64 + i * 16) * 64 + c1);
    }
    if (t + 2 < NT) stage(ABIT ? 2 : 1, b, t + 2);
    __builtin_amdgcn_s_barrier();
    asm volatile("s_waitcnt lgkmcnt(0)" ::: "memory");
    __builtin_amdgcn_sched_barrier(0);
    __builtin_amdgcn_s_setprio(1);
#pragma unroll
    for (int s = 0; s < 2; ++s)
#pragma unroll
      for (int i = 0; i < 4; ++i)
#pragma unroll
        for (int j = 0; j < 2; ++j)
          acc[i + 4][j] = __builtin_amdgcn_mfma_f32_16x16x32_bf16(af[i][s], bf1[j][s], acc[i + 4][j], 0, 0, 0);
    __builtin_amdgcn_s_setprio(0);
    __builtin_amdgcn_s_barrier();

    // ---- P4: expand A(t+1) [ABIT] / stage B2(t+2) [non-ABIT]; MFMA C4 ----
    if (ABIT) { if (t + 1 < NT) expandA(t + 1); }
    else      { if (t + 2 < NT) stage(2, b, t + 2); }
    __builtin_amdgcn_s_barrier();
    __builtin_amdgcn_s_setprio(1);
#pragma unroll
    for (int s = 0; s < 2; ++s)
#pragma unroll
      for (int i = 0; i < 4; ++i)
#pragma unroll
        for (int j = 0; j < 2; ++j)
          acc[i + 4][j + 2] = __builtin_amdgcn_mfma_f32_16x16x32_bf16(af[i][s], bf2[j][s], acc[i + 4][j + 2], 0, 0, 0);
    __builtin_amdgcn_s_setprio(0);
    if (ABIT) {
      if (t + 2 < NT) { asm volatile("s_waitcnt vmcnt(4) lgkmcnt(0)" ::: "memory"); }
      else            { asm volatile("s_waitcnt vmcnt(0) lgkmcnt(0)" ::: "memory"); }
    } else {
      if (t + 2 < NT)      { asm volatile("s_waitcnt vmcnt(6)" ::: "memory"); }
      else if (t + 1 < NT) { asm volatile("s_waitcnt vmcnt(0)" ::: "memory"); }
    }
    __builtin_amdgcn_s_barrier();
  }

  if (EPI == 0) {
#pragma unroll
    for (int i = 0; i < 8; ++i)
#pragma unroll
      for (int j = 0; j < 4; ++j) {
        int col = n0 + wc * 64 + j * 16 + lm;
        float bias = bias0[col];
#pragma unroll
        for (int r = 0; r < 4; ++r) {
          int row = m0 + wr * 128 + i * 16 + lq * 4 + r;
          float v = acc[i][j][r] + bias;
          outb[(size_t)row * N + col] = f32_to_bf16(fmaxf(v, 0.f));
        }
      }
  } else {
    const int wpr = N >> 4;   // bitmask words per row
#pragma unroll
    for (int i = 0; i < 8; ++i) {
      float rs[4] = {0.f, 0.f, 0.f, 0.f};
#pragma unroll
      for (int j = 0; j < 4; ++j) {
        int col = n0 + wc * 64 + j * 16 + lm;
        float bias = bias0[col];
        int w16 = (col >> 4);
#pragma unroll
        for (int r = 0; r < 4; ++r) {
          int row = m0 + wr * 128 + i * 16 + lq * 4 + r;
          float l = acc[i][j][r] + bias;
          unsigned short mask = xbit[(size_t)row * wpr + w16];  // broadcast
          float tt = ((mask >> lm) & 1) ? -l : l;
          float sp = fmaxf(tt, 0.f) + __logf(1.f + __expf(-fabsf(tt)));
          rs[r] -= sp;
        }
      }
#pragma unroll
      for (int off = 1; off < 16; off <<= 1)
#pragma unroll
        for (int r = 0; r < 4; ++r) rs[r] += __shfl_xor(rs[r], off, 64);
      if (lm == 0) {
#pragma unroll
        for (int r = 0; r < 4; ++r)
          atomicAdd(&outf[m0 + wr * 128 + i * 16 + lq * 4 + r], rs[r]);
      }
    }
  }
}

// -------- latent_fused: S2 = h @ w2t^T (N=256) -> z/kl -> hd = relu(z@Wd1+bd1) --------
// One block per 64 batch rows (grid 512), 256 thr / 4 waves, 2 blocks/CU.
// R16 part 1: wave = 64 rows x 64 cols, col-tiles {2w,2w+1,2w+8,2w+9} ->
// 4 A + 4 B ds_reads per 16 MFMA (was 1+16); mu/ls stay paired in-lane
// (acc[i][j] mu, acc[i][j+2] ls). kl rowsum crosses waves via klbuf (LDS).
// Part 2 unchanged: wd1t staged in 128-col halves, K=128 MFMA.
__global__ __launch_bounds__(256, 2) void latent_fused(
    const unsigned short* A,                  // h [B][1024] (also hd output)
    const unsigned short* __restrict__ BT,    // w2t [256][1024]
    const unsigned short* __restrict__ WD1,   // wd1t [1024][128]
    const float* __restrict__ bmu, const float* __restrict__ bls,
    const float* __restrict__ bd1,
    const float* __restrict__ eps,            // [B][128]
    unsigned short* hd,                       // [B][1024] (= h buffer)
    float* __restrict__ out) {
  __shared__ __align__(16) unsigned short smem[29184];   // 57 KB
  unsigned short* As0 = smem;              // [64*32]   0..2047
  unsigned short* As1 = smem + 2048;       // [64*32]   2048..4095
  unsigned short* Bs0 = smem + 4096;       // [256*32]  4096..12287
  unsigned short* Bs1 = smem + 12288;      // [256*32]  12288..20479
  unsigned short* zs  = smem + 20480;      // [64*128]  20480..28671
  float* klbuf = reinterpret_cast<float*>(smem + 28672);  // [4][64] f32, 1 KB
  unsigned short* Bs2 = smem;              // [128*128] part 2 (overlays As+Bs)

  const int K = 1024;
  const int tid = threadIdx.x;
  const int lane = tid & 63;
  const int wave = tid >> 6;
  const int m0 = blockIdx.x * 64;
  const int lm = lane & 15, lq = lane >> 4;
  const int sw2 = (lm >> 1) & 3;           // BK=32 read swizzle (R7 pattern)

  // ---- part 1 staging: A 256 chunks (1/thread), B 1024 chunks (4/thread)
  const unsigned short* agp;
  const unsigned short* bgp[4];
  {
    int row = tid >> 2, q = tid & 3;
    agp = A + (size_t)(m0 + row) * K + (q ^ ((row >> 1) & 3)) * 8;
  }
#pragma unroll
  for (int r = 0; r < 4; ++r) {
    int c = tid + 256 * r;
    int row = c >> 2, q = c & 3;
    bgp[r] = BT + (size_t)row * K + (q ^ ((row >> 1) & 3)) * 8;
  }

  auto stage1 = [&](int buf, int kt) {
    gl_lds16(agp + kt, (buf ? As1 : As0) + tid * 8);
    unsigned short* Bd = buf ? Bs1 : Bs0;
#pragma unroll
    for (int r = 0; r < 4; ++r) gl_lds16(bgp[r] + kt, Bd + (tid + 256 * r) * 8);
  };

  f32x4 acc[4][4] = {};   // [row-frag i: rows i*16][col-frag j: mu j<2, ls j+2]

  stage1(0, 0);
  __syncthreads();

  const int cOff = (lq ^ sw2) * 8;   // within-row chunk offset (row = 64 B)
  for (int t = 0; t < 32; ++t) {
    const int cur = t & 1;
    if (t + 1 < 32) stage1(cur ^ 1, (t + 1) * 32);   // full-tile window
    const unsigned short* Ab = cur ? As1 : As0;
    const unsigned short* Bb = cur ? Bs1 : Bs0;
    bf16x8 af[4], bfr[4];
#pragma unroll
    for (int i = 0; i < 4; ++i)
      af[i] = *reinterpret_cast<const bf16x8*>(Ab + (i * 16 + lm) * 32 + cOff);
#pragma unroll
    for (int j = 0; j < 4; ++j) {
      int jj = (j < 2) ? (2 * wave + j) : (8 + 2 * wave + (j - 2));
      bfr[j] = *reinterpret_cast<const bf16x8*>(Bb + (jj * 16 + lm) * 32 + cOff);
    }
#pragma unroll
    for (int i = 0; i < 4; ++i)
#pragma unroll
      for (int j = 0; j < 4; ++j)
        acc[i][j] = __builtin_amdgcn_mfma_f32_16x16x32_bf16(af[i], bfr[j], acc[i][j], 0, 0, 0);
    __syncthreads();   // implicit vmcnt(0): stage had a full tile to land
  }

  // part 2 staging: wd1t half [128 rows][128 k] -> Bs2; row = 256 B = 16
  // chunks; slot s of row r holds global chunk s ^ (r&7). 8 chunks/thread.
  auto stage2 = [&](int hh) {
#pragma unroll
    for (int ri = 0; ri < 8; ++ri) {
      int c = tid + 256 * ri;
      int row = c >> 4, slot = c & 15;
      int gc = slot ^ (row & 7);
      gl_lds16(WD1 + (size_t)(hh * 128 + row) * 128 + gc * 8, Bs2 + c * 8);
    }
  };
  stage2(0);   // overlays dead part-1 buffers; overlaps the z/kl epilogue

  // ---- part 1 epilogue: z -> zs (swizzled), kl partials -> klbuf ----
#pragma unroll
  for (int i = 0; i < 4; ++i) {
    float kl[4] = {0.f, 0.f, 0.f, 0.f};
#pragma unroll
    for (int j = 0; j < 2; ++j) {
      int dim = (2 * wave + j) * 16 + lm;         // this wave's mu dim
      float bm = bmu[dim], bl = bls[dim];
#pragma unroll
      for (int r = 0; r < 4; ++r) {
        int rowl = i * 16 + lq * 4 + r;           // local row (0..63)
        float mu = acc[i][j][r] + bm;
        float ls = acc[i][j + 2][r] + bl;
        float e = eps[(size_t)(m0 + rowl) * 128 + dim];
        float zv = fmaf(__expf(ls), e, mu);
        int chunk = (dim >> 3);
        int slot = chunk ^ (rowl & 7);
        zs[rowl * 128 + slot * 8 + (lm & 7)] = f32_to_bf16(zv);
        kl[r] += 0.5f * (__expf(2.f * ls) + mu * mu - 2.f * ls - 1.f);
      }
    }
    // reduce across lm (16 lanes = this wave's 32 dims incl. j-loop above)
#pragma unroll
    for (int off = 1; off < 16; off <<= 1)
#pragma unroll
      for (int r = 0; r < 4; ++r) kl[r] += __shfl_xor(kl[r], off, 64);
    if (lm == 0) {
#pragma unroll
      for (int r = 0; r < 4; ++r)
        klbuf[wave * 64 + i * 16 + lq * 4 + r] = kl[r];
    }
  }
  __syncthreads();          // klbuf + zs complete
  if (tid < 64) {
    float s = klbuf[tid] + klbuf[64 + tid] + klbuf[128 + tid] + klbuf[192 + tid];
    out[m0 + tid] = -s;
  }

  // ---- part 2: hd = relu(z @ wd1t^T + bd1), 8 half-tiles of 128 cols ----
  for (int hh = 0; hh < 8; ++hh) {
    asm volatile("s_waitcnt vmcnt(0)" ::: "memory");
    __syncthreads();                       // Bs2[hh] staged; zs visible (hh=0)
    f32x4 acc2[8] = {};
#pragma unroll
    for (int ks = 0; ks < 4; ++ks) {
      const int cks = (ks * 4 + lq) ^ (lm & 7);
      bf16x8 a0 = *reinterpret_cast<const bf16x8*>(zs + (wave * 16 + lm) * 128 + cks * 8);
#pragma unroll
      for (int j = 0; j < 8; ++j) {
        bf16x8 b = *reinterpret_cast<const bf16x8*>(Bs2 + (j * 16 + lm) * 128 + cks * 8);
        acc2[j] = __builtin_amdgcn_mfma_f32_16x16x32_bf16(a0, b, acc2[j], 0, 0, 0);
      }
    }
    __syncthreads();                       // all waves done reading Bs2
    if (hh + 1 < 8) stage2(hh + 1);        // latency hidden under hd writes
#pragma unroll
    for (int j = 0; j < 8; ++j) {
      int col = hh * 128 + j * 16 + lm;
      float bias = bd1[col];
#pragma unroll
      for (int r = 0; r < 4; ++r) {
        int row = m0 + wave * 16 + lq * 4 + r;
        float v = acc2[j][r] + bias;
        hd[(size_t)row * 1024 + col] = f32_to_bf16(fmaxf(v, 0.f));
      }
    }
  }
}

extern "C" void kernel_launch(void* const* d_in, const int* in_sizes, int n_in,
                              void* d_out, int out_size, void* d_ws, size_t ws_size,
                              hipStream_t stream) {
  const float* x   = (const float*)d_in[0];
  const float* eps = (const float*)d_in[1];
  const float* We1 = (const float*)d_in[2];
  const float* be1 = (const float*)d_in[3];
  const float* Wmu = (const float*)d_in[4];
  const float* bmu = (const float*)d_in[5];
  const float* Wls = (const float*)d_in[6];
  const float* bls = (const float*)d_in[7];
  const float* Wd1 = (const float*)d_in[8];
  const float* bd1 = (const float*)d_in[9];
  const float* Wd2 = (const float*)d_in[10];
  const float* bd2 = (const float*)d_in[11];
  float* out = (float*)d_out;

  const int B = 32768, D = 1024, H = 1024, L = 128;

  char* ws = (char*)d_ws;
  size_t off = 0;
  auto alloc = [&](size_t bytes) {
    void* p = ws + off;
    off += (bytes + 255) & ~(size_t)255;
    return p;
  };
  unsigned short* xbit = (unsigned short*)alloc((size_t)B * D / 8);   // 4 MB
  unsigned short* w1t  = (unsigned short*)alloc((size_t)H * D * 2);   // 2 MB  [H][D]
  unsigned short* w2t  = (unsigned short*)alloc((size_t)256 * H * 2); // 0.5MB [256][H]
  unsigned short* wd1t = (unsigned short*)alloc((size_t)H * L * 2);   // .25MB [H][L]
  unsigned short* wd2t = (unsigned short*)alloc((size_t)D * H * 2);   // 2 MB  [D][H]
  unsigned short* h    = (unsigned short*)alloc((size_t)B * H * 2);   // 64 MB
  unsigned short* hd   = h;  // h consumed in-block by latent_fused -> reuse

  TransJob j0{We1, w1t, D, H, 1024};
  TransJob j1{Wmu, w2t, H, L, 1152};
  TransJob j2{Wls, w2t + 128 * H, H, L, 1280};
  TransJob j3{Wd1, wd1t, L, H, 1408};
  TransJob j4{Wd2, wd2t, H, D, 2432};
  // one dispatch: 2432 transpose blocks + 2048 bitpack blocks
  prep_k<<<2432 + 2048, dim3(32, 8), 0, stream>>>(
      j0, j1, j2, j3, j4, x, xbit, B * D / 4, 2048);

  // GEMM1: h = relu(x @ We1 + be1)   [M=32768, N=1024, K=1024], A from xbit
  gemm256<0, 1, 1><<<512, 512, 0, stream>>>(
      nullptr, w1t, 4, H, D, be1, h, nullptr, xbit);
  // latent: mu/ls -> z (LDS) -> kl -> hd = relu(z @ Wd1 + bd1)
  latent_fused<<<B / 64, 256, 0, stream>>>(
      h, w2t, wd1t, bmu, bls, bd1, eps, hd, out);
  // GEMM4: bernoulli log-likelihood accumulated into out [K=1024] (control)
  gemm256<2, 4, 0><<<512, 512, 0, stream>>>(
      hd, wd2t, 4, D, H, bd2, nullptr, out, xbit);

  (void)in_sizes; (void)n_in; (void)out_size; (void)ws_size;
}